// Round 1
// baseline (449.963 us; speedup 1.0000x reference)
//
#include <hip/hip_runtime.h>
#include <hip/hip_bf16.h>
#include <stdint.h>
#include <stddef.h>

// Problem dims (fixed by setup_inputs): x [4,2048,4096] f32, W [4096,4096] f32, b [4096] f32
#define DIN   4096
#define DOUT  4096
#define MTOK  8192   // 4*2048 tokens
#define NW4   4194304   // W element count / 4  (16777216/4)

typedef __attribute__((ext_vector_type(4))) int   i32x4;
typedef __attribute__((ext_vector_type(4))) float f32x4;

// ws layout (bytes)
#define OFF_SUM 0                       // double      (zeroed via memset)
#define OFF_WS  8                       // float wscale
#define OFF_F   256                     // float f[8192]
#define OFF_QX  65536                   // int8 qX[8192][4096]
#define OFF_QW  (65536 + 8192*4096)     // int8 qW[4096][4096]

// ---------------- kernel 1: sum |W| in fp64 ----------------
__global__ __launch_bounds__(256) void k_sumabs(const float* __restrict__ W,
                                                double* __restrict__ sum) {
  int idx = blockIdx.x * 256 + threadIdx.x;       // 2048 blocks -> 524288 threads
  const f32x4* W4 = (const f32x4*)W;
  double s = 0.0;
#pragma unroll
  for (int i = 0; i < 8; ++i) {
    f32x4 v = W4[idx + i * 524288];
    s += (double)fabsf(v[0]);
    s += (double)fabsf(v[1]);
    s += (double)fabsf(v[2]);
    s += (double)fabsf(v[3]);
  }
#pragma unroll
  for (int off = 32; off > 0; off >>= 1) s += __shfl_xor(s, off);
  __shared__ double wsum[4];
  int lane = threadIdx.x & 63, w = threadIdx.x >> 6;
  if (lane == 0) wsum[w] = s;
  __syncthreads();
  if (threadIdx.x == 0) atomicAdd(sum, wsum[0] + wsum[1] + wsum[2] + wsum[3]);
}

// ---------------- kernel 2: finalize weight scale ----------------
__global__ void k_wscale(const double* __restrict__ sum, float* __restrict__ wsc) {
  double mean = *sum / 16777216.0;
  float s = (float)mean;
  if (s < 1e-6f) s = 1e-6f;
  *wsc = s;
}

// ---------------- kernel 3: ternary-quantize W ----------------
__global__ __launch_bounds__(256) void k_quantw(const float* __restrict__ W,
                                                const float* __restrict__ wsc,
                                                char* __restrict__ qW) {
  int idx = blockIdx.x * 256 + threadIdx.x;       // 16384 blocks -> one float4 each
  float s = *wsc;
  f32x4 v = ((const f32x4*)W)[idx];
  int q0 = (int)fminf(fmaxf(rintf(v[0] / s), -1.f), 1.f);
  int q1 = (int)fminf(fmaxf(rintf(v[1] / s), -1.f), 1.f);
  int q2 = (int)fminf(fmaxf(rintf(v[2] / s), -1.f), 1.f);
  int q3 = (int)fminf(fmaxf(rintf(v[3] / s), -1.f), 1.f);
  uint32_t packed = (uint32_t)(q0 & 255) | ((uint32_t)(q1 & 255) << 8) |
                    ((uint32_t)(q2 & 255) << 16) | ((uint32_t)(q3 & 255) << 24);
  ((uint32_t*)qW)[idx] = packed;
}

// ---------------- kernel 4: per-token absmax int8 quant of x ----------------
__global__ __launch_bounds__(256) void k_quantx(const float* __restrict__ x,
                                                const float* __restrict__ wsc,
                                                char* __restrict__ qX,
                                                float* __restrict__ f) {
  int tok = blockIdx.x;                            // 8192 blocks
  int t = threadIdx.x;
  const f32x4* xr = (const f32x4*)(x + (size_t)tok * DIN);
  f32x4 v[4];
  float m = 0.f;
#pragma unroll
  for (int i = 0; i < 4; ++i) {
    v[i] = xr[t + 256 * i];
    m = fmaxf(m, fmaxf(fmaxf(fabsf(v[i][0]), fabsf(v[i][1])),
                       fmaxf(fabsf(v[i][2]), fabsf(v[i][3]))));
  }
#pragma unroll
  for (int off = 32; off > 0; off >>= 1) m = fmaxf(m, __shfl_xor(m, off));
  __shared__ float wm[4];
  if ((t & 63) == 0) wm[t >> 6] = m;
  __syncthreads();
  m = fmaxf(fmaxf(wm[0], wm[1]), fmaxf(wm[2], wm[3]));
  m = fmaxf(m, 1e-6f);
  float s = 127.0f / m;
  uint32_t* qr = (uint32_t*)(qX + (size_t)tok * DIN);
#pragma unroll
  for (int i = 0; i < 4; ++i) {
    int q0 = (int)fminf(fmaxf(rintf(v[i][0] * s), -128.f), 127.f);
    int q1 = (int)fminf(fmaxf(rintf(v[i][1] * s), -128.f), 127.f);
    int q2 = (int)fminf(fmaxf(rintf(v[i][2] * s), -128.f), 127.f);
    int q3 = (int)fminf(fmaxf(rintf(v[i][3] * s), -128.f), 127.f);
    uint32_t packed = (uint32_t)(q0 & 255) | ((uint32_t)(q1 & 255) << 8) |
                      ((uint32_t)(q2 & 255) << 16) | ((uint32_t)(q3 & 255) << 24);
    qr[t + 256 * i] = packed;
  }
  if (t == 0) f[tok] = (*wsc) * (m / 127.0f);
}

// ---------------- kernel 5: i8 GEMM  C[m][n] = (qX[m]·qW[n]) * f[m] + b[n] ----
// m97-proven structure: 128x128 tile, BK=64, 4 waves (2x2), global_load_lds w16.
#define BM 128
#define BN 128
#define BK 64

__device__ __forceinline__ void gload16(const void* g, void* l) {
  __builtin_amdgcn_global_load_lds(
      (const __attribute__((address_space(1))) void*)g,
      (__attribute__((address_space(3))) void*)l, 16, 0, 0);
}

__global__ __launch_bounds__(256) void k_gemm(const char* __restrict__ qX,
                                              const char* __restrict__ qW,
                                              const float* __restrict__ f,
                                              const float* __restrict__ bias,
                                              float* __restrict__ out) {
  int bid = blockIdx.x;                       // 2048 blocks = 64 (M) x 32 (N)
  int swz = (bid & 7) * 256 + (bid >> 3);     // XCD-bijective (2048 % 8 == 0)
  int bmi = swz >> 5;                         // 0..63
  int bni = swz & 31;                         // 0..31
  int bm0 = bmi * BM, bn0 = bni * BN;

  __shared__ char smem[16384];                // A: [0,8K) 128x64B, B: [8K,16K)

  const int t = threadIdx.x;
  const int lane = t & 63;
  const int w = t >> 6;                       // wave 0..3
  const int wm = w >> 1, wn = w & 1;          // 2x2 wave grid, 64x64 each

  i32x4 acc[4][4] = {};

  // staging source addressing: thread t handles row t/4, 16B chunk t%4 (per pass)
  const int rs = t >> 2;                      // 0..63
  const int cs = (t & 3) << 4;                // 0,16,32,48
  const char* srcA = qX + (size_t)(bm0 + rs) * DIN + cs;
  const char* srcB = qW + (size_t)(bn0 + rs) * DIN + cs;
  char* dstA0 = smem + w * 1024;
  char* dstA1 = smem + 4096 + w * 1024;
  char* dstB0 = smem + 8192 + w * 1024;
  char* dstB1 = smem + 12288 + w * 1024;

  // fragment read addressing
  const char* baseA = smem + (size_t)(wm * 64 + (lane & 15)) * 64 + ((lane >> 4) << 4);
  const char* baseB = smem + 8192 + (size_t)(wn * 64 + (lane & 15)) * 64 + ((lane >> 4) << 4);

  for (int kt = 0; kt < DIN / BK; ++kt) {
    const int k0 = kt * BK;
    gload16(srcA + k0, dstA0);
    gload16(srcA + (size_t)64 * DIN + k0, dstA1);
    gload16(srcB + k0, dstB0);
    gload16(srcB + (size_t)64 * DIN + k0, dstB1);
    __syncthreads();

    i32x4 a[4], b[4];
#pragma unroll
    for (int i = 0; i < 4; ++i) a[i] = *(const i32x4*)(baseA + i * 16 * 64);
#pragma unroll
    for (int j = 0; j < 4; ++j) b[j] = *(const i32x4*)(baseB + j * 16 * 64);
#pragma unroll
    for (int i = 0; i < 4; ++i)
#pragma unroll
      for (int j = 0; j < 4; ++j)
        acc[i][j] = __builtin_amdgcn_mfma_i32_16x16x64_i8(a[i], b[j], acc[i][j], 0, 0, 0);
    __syncthreads();
  }

  // epilogue: C[m][n] = acc * f[m] + bias[n]
  const int col0 = bn0 + wn * 64 + (lane & 15);
  const int row0 = bm0 + wm * 64 + ((lane >> 4) << 2);
  float bj[4];
#pragma unroll
  for (int j = 0; j < 4; ++j) bj[j] = bias[col0 + j * 16];
#pragma unroll
  for (int i = 0; i < 4; ++i) {
#pragma unroll
    for (int q = 0; q < 4; ++q) {
      const int m = row0 + i * 16 + q;
      const float fm = f[m];
      float* orow = out + (size_t)m * DOUT;
#pragma unroll
      for (int j = 0; j < 4; ++j)
        orow[col0 + j * 16] = (float)acc[i][j][q] * fm + bj[j];
    }
  }
}

extern "C" void kernel_launch(void* const* d_in, const int* in_sizes, int n_in,
                              void* d_out, int out_size, void* d_ws, size_t ws_size,
                              hipStream_t stream) {
  const float* x    = (const float*)d_in[0];
  const float* W    = (const float*)d_in[1];
  const float* bias = (const float*)d_in[2];
  float* out = (float*)d_out;
  char* ws = (char*)d_ws;

  double* sum = (double*)(ws + OFF_SUM);
  float* wsc  = (float*)(ws + OFF_WS);
  float* f    = (float*)(ws + OFF_F);
  char* qX    = ws + OFF_QX;
  char* qW    = ws + OFF_QW;

  hipMemsetAsync(d_ws, 0, 256, stream);
  k_sumabs<<<2048, 256, 0, stream>>>(W, sum);
  k_wscale<<<1, 1, 0, stream>>>(sum, wsc);
  k_quantw<<<16384, 256, 0, stream>>>(W, wsc, qW);
  k_quantx<<<8192, 256, 0, stream>>>(x, wsc, qX, f);
  k_gemm<<<2048, 256, 0, stream>>>(qX, qW, f, bias, out);
}